// Round 1
// baseline (1461.562 us; speedup 1.0000x reference)
//
#include <hip/hip_runtime.h>
#include <hip/hip_bf16.h>
#include <math.h>

// MultiHeadDiffAttention, MI355X. Round 1: correct fp32 baseline.
// B=2 S=2048 E=1024 H=8 DH=128 F=64. Pipeline:
//   1. Q,K,V = x @ W{q,k,v}.T           (one GEMM kernel, gridDim.z selects)
//   2. fused two-branch flash attention  -> O [B,S,H,DH]
//   3. RMSNorm over (H,DH) per (b,s), in-place on O
//   4. out = (O @ Wo.T + bo) * (1-dw)    (same GEMM kernel, final_mode=1)
// Workspace: Q,K,V,O fp32 = 4 * 16 MB = 64 MB.

#define SDIM 2048
#define EDIM 1024
#define HDIM 8
#define DHDIM 128

// ------------------------------------------------------------------
// GEMM: C[M,N] = A[M,K] @ W[N,K]^T   (M=4096, N=K=1024, all fixed)
// 128x128 block, BK=16, 256 threads, 8x8 micro-tile per thread.
// ------------------------------------------------------------------
constexpr int GM = 4096, GN = 1024, GK = 1024;
constexpr int BM = 128, BN = 128, BK = 16;

__global__ __launch_bounds__(256) void gemm_kernel(
    const float* __restrict__ A,
    const float* __restrict__ W0, const float* __restrict__ W1, const float* __restrict__ W2,
    float* __restrict__ C0, float* __restrict__ C1, float* __restrict__ C2,
    const float* __restrict__ bias, const float* __restrict__ dwp, int final_mode)
{
    const float* W = (blockIdx.z == 0) ? W0 : ((blockIdx.z == 1) ? W1 : W2);
    float* C = (blockIdx.z == 0) ? C0 : ((blockIdx.z == 1) ? C1 : C2);

    __shared__ float As[BK][BM + 4];
    __shared__ float Bs[BK][BN + 4];

    const int tid = threadIdx.x;
    const int tx = tid & 15;
    const int ty = tid >> 4;
    const int m0 = blockIdx.y * BM;
    const int n0 = blockIdx.x * BN;

    float acc[8][8];
#pragma unroll
    for (int i = 0; i < 8; ++i)
#pragma unroll
        for (int j = 0; j < 8; ++j) acc[i][j] = 0.f;

    for (int k0 = 0; k0 < GK; k0 += BK) {
        // stage A-tile (128x16) and W-tile (128x16), transposed into LDS
#pragma unroll
        for (int l = 0; l < 2; ++l) {
            int idx = tid + l * 256;          // 0..511 float4 slots
            int row = idx >> 2;               // 0..127
            int c4  = (idx & 3) << 2;         // 0,4,8,12
            float4 va = *(const float4*)&A[(size_t)(m0 + row) * GK + k0 + c4];
            As[c4 + 0][row] = va.x; As[c4 + 1][row] = va.y;
            As[c4 + 2][row] = va.z; As[c4 + 3][row] = va.w;
            float4 vb = *(const float4*)&W[(size_t)(n0 + row) * GK + k0 + c4];
            Bs[c4 + 0][row] = vb.x; Bs[c4 + 1][row] = vb.y;
            Bs[c4 + 2][row] = vb.z; Bs[c4 + 3][row] = vb.w;
        }
        __syncthreads();
#pragma unroll
        for (int kk = 0; kk < BK; ++kk) {
            float4 a0 = *(const float4*)&As[kk][ty * 8];
            float4 a1 = *(const float4*)&As[kk][ty * 8 + 4];
            float4 b0 = *(const float4*)&Bs[kk][tx * 8];
            float4 b1 = *(const float4*)&Bs[kk][tx * 8 + 4];
            float a[8] = {a0.x, a0.y, a0.z, a0.w, a1.x, a1.y, a1.z, a1.w};
            float b[8] = {b0.x, b0.y, b0.z, b0.w, b1.x, b1.y, b1.z, b1.w};
#pragma unroll
            for (int i = 0; i < 8; ++i)
#pragma unroll
                for (int j = 0; j < 8; ++j)
                    acc[i][j] = fmaf(a[i], b[j], acc[i][j]);
        }
        __syncthreads();
    }

    float scale = 1.0f;
    float bv[8] = {0.f, 0.f, 0.f, 0.f, 0.f, 0.f, 0.f, 0.f};
    if (final_mode) {
        scale = 1.0f - dwp[0];
#pragma unroll
        for (int j = 0; j < 8; ++j) bv[j] = bias[n0 + tx * 8 + j];
    }
#pragma unroll
    for (int i = 0; i < 8; ++i) {
        float o[8];
#pragma unroll
        for (int j = 0; j < 8; ++j) o[j] = (acc[i][j] + bv[j]) * scale;
        float4* dst = (float4*)&C[(size_t)(m0 + ty * 8 + i) * GN + n0 + tx * 8];
        dst[0] = make_float4(o[0], o[1], o[2], o[3]);
        dst[1] = make_float4(o[4], o[5], o[6], o[7]);
    }
}

// ------------------------------------------------------------------
// Fused two-branch diff flash attention.
// Grid: (S/32, B*H). Block 256 = 16x16: thread owns 2 q-rows x
// (2 score cols | 8 o-cols). Per-branch online softmax; P via LDS.
// ------------------------------------------------------------------
constexpr int BQ = 32, BKV = 32;

__device__ __forceinline__ float dot4(float4 a, float4 b) {
    return a.x * b.x + a.y * b.y + a.z * b.z + a.w * b.w;
}

__global__ __launch_bounds__(256) void attn_kernel(
    const float* __restrict__ Q, const float* __restrict__ K,
    const float* __restrict__ V, float* __restrict__ O,
    const float* __restrict__ dwp)
{
    const int bh = blockIdx.y;            // b*H + h
    const int b  = bh >> 3;
    const int h  = bh & 7;
    const int q0 = blockIdx.x * BQ;
    const size_t base = (size_t)b * SDIM * EDIM;
    const int hoff = h * DHDIM;

    __shared__ float Qs[BQ][DHDIM + 4];
    __shared__ float Ks[BKV][DHDIM + 4];
    __shared__ float Vs[BKV][DHDIM + 4];
    __shared__ float P0s[BQ][BKV + 4];
    __shared__ float P1s[BQ][BKV + 4];

    const int tid = threadIdx.x;
    const int tx = tid & 15;
    const int ty = tid >> 4;
    const int r0 = ty * 2;       // score/acc rows
    const int c0 = tx * 2;       // score cols

    // stage Q tile: 32 rows x 128 floats
#pragma unroll
    for (int l = 0; l < 4; ++l) {
        int idx = tid + l * 256;         // 0..1023 float4 slots
        int row = idx >> 5;
        int c   = (idx & 31) << 2;
        *(float4*)&Qs[row][c] =
            *(const float4*)&Q[base + (size_t)(q0 + row) * EDIM + hoff + c];
    }

    float m0v[2] = {-1e30f, -1e30f}, m1v[2] = {-1e30f, -1e30f};
    float l0v[2] = {0.f, 0.f},       l1v[2] = {0.f, 0.f};
    float acc0[2][8], acc1[2][8];
#pragma unroll
    for (int i = 0; i < 2; ++i)
#pragma unroll
        for (int j = 0; j < 8; ++j) { acc0[i][j] = 0.f; acc1[i][j] = 0.f; }

    const float scl = 0.125f;   // F^-0.5, F=64

    for (int k0 = 0; k0 < SDIM; k0 += BKV) {
        __syncthreads();   // protect Ks/Vs (and P vs prior PV reads)
#pragma unroll
        for (int l = 0; l < 4; ++l) {
            int idx = tid + l * 256;
            int row = idx >> 5;
            int c   = (idx & 31) << 2;
            *(float4*)&Ks[row][c] =
                *(const float4*)&K[base + (size_t)(k0 + row) * EDIM + hoff + c];
            *(float4*)&Vs[row][c] =
                *(const float4*)&V[base + (size_t)(k0 + row) * EDIM + hoff + c];
        }
        __syncthreads();

        // ---- scores: 2x2 per thread, per branch ----
        float s0[2][2] = {{0.f,0.f},{0.f,0.f}};
        float s1[2][2] = {{0.f,0.f},{0.f,0.f}};
#pragma unroll
        for (int f4 = 0; f4 < 16; ++f4) {
            int f = f4 * 4;
            float4 qa = *(const float4*)&Qs[r0][f];
            float4 qb = *(const float4*)&Qs[r0 + 1][f];
            float4 ka = *(const float4*)&Ks[c0][f];
            float4 kb = *(const float4*)&Ks[c0 + 1][f];
            s0[0][0] += dot4(qa, ka); s0[0][1] += dot4(qa, kb);
            s0[1][0] += dot4(qb, ka); s0[1][1] += dot4(qb, kb);
            float4 qa1 = *(const float4*)&Qs[r0][64 + f];
            float4 qb1 = *(const float4*)&Qs[r0 + 1][64 + f];
            float4 ka1 = *(const float4*)&Ks[c0][64 + f];
            float4 kb1 = *(const float4*)&Ks[c0 + 1][64 + f];
            s1[0][0] += dot4(qa1, ka1); s1[0][1] += dot4(qa1, kb1);
            s1[1][0] += dot4(qb1, ka1); s1[1][1] += dot4(qb1, kb1);
        }
#pragma unroll
        for (int i = 0; i < 2; ++i)
#pragma unroll
            for (int j = 0; j < 2; ++j) { s0[i][j] *= scl; s1[i][j] *= scl; }

        // ---- online softmax, branch 0 ----
#pragma unroll
        for (int i = 0; i < 2; ++i) {
            float a = fmaxf(s0[i][0], s0[i][1]);
            a = fmaxf(a, __shfl_xor(a, 1, 16));
            a = fmaxf(a, __shfl_xor(a, 2, 16));
            a = fmaxf(a, __shfl_xor(a, 4, 16));
            a = fmaxf(a, __shfl_xor(a, 8, 16));
            float mnew  = fmaxf(m0v[i], a);
            float alpha = __expf(m0v[i] - mnew);
            float p0 = __expf(s0[i][0] - mnew);
            float p1 = __expf(s0[i][1] - mnew);
            float rs = p0 + p1;
            rs += __shfl_xor(rs, 1, 16);
            rs += __shfl_xor(rs, 2, 16);
            rs += __shfl_xor(rs, 4, 16);
            rs += __shfl_xor(rs, 8, 16);
            l0v[i] = l0v[i] * alpha + rs;
            m0v[i] = mnew;
#pragma unroll
            for (int j = 0; j < 8; ++j) acc0[i][j] *= alpha;
            P0s[r0 + i][c0]     = p0;
            P0s[r0 + i][c0 + 1] = p1;
        }
        // ---- online softmax, branch 1 ----
#pragma unroll
        for (int i = 0; i < 2; ++i) {
            float a = fmaxf(s1[i][0], s1[i][1]);
            a = fmaxf(a, __shfl_xor(a, 1, 16));
            a = fmaxf(a, __shfl_xor(a, 2, 16));
            a = fmaxf(a, __shfl_xor(a, 4, 16));
            a = fmaxf(a, __shfl_xor(a, 8, 16));
            float mnew  = fmaxf(m1v[i], a);
            float alpha = __expf(m1v[i] - mnew);
            float p0 = __expf(s1[i][0] - mnew);
            float p1 = __expf(s1[i][1] - mnew);
            float rs = p0 + p1;
            rs += __shfl_xor(rs, 1, 16);
            rs += __shfl_xor(rs, 2, 16);
            rs += __shfl_xor(rs, 4, 16);
            rs += __shfl_xor(rs, 8, 16);
            l1v[i] = l1v[i] * alpha + rs;
            m1v[i] = mnew;
#pragma unroll
            for (int j = 0; j < 8; ++j) acc1[i][j] *= alpha;
            P1s[r0 + i][c0]     = p0;
            P1s[r0 + i][c0 + 1] = p1;
        }
        __syncthreads();

        // ---- PV accumulate: acc[i][0..7] over kk ----
#pragma unroll 4
        for (int kk = 0; kk < BKV; ++kk) {
            float4 va = *(const float4*)&Vs[kk][tx * 8];
            float4 vb = *(const float4*)&Vs[kk][tx * 8 + 4];
#pragma unroll
            for (int i = 0; i < 2; ++i) {
                float p0 = P0s[r0 + i][kk];
                float p1 = P1s[r0 + i][kk];
                acc0[i][0] = fmaf(p0, va.x, acc0[i][0]);
                acc0[i][1] = fmaf(p0, va.y, acc0[i][1]);
                acc0[i][2] = fmaf(p0, va.z, acc0[i][2]);
                acc0[i][3] = fmaf(p0, va.w, acc0[i][3]);
                acc0[i][4] = fmaf(p0, vb.x, acc0[i][4]);
                acc0[i][5] = fmaf(p0, vb.y, acc0[i][5]);
                acc0[i][6] = fmaf(p0, vb.z, acc0[i][6]);
                acc0[i][7] = fmaf(p0, vb.w, acc0[i][7]);
                acc1[i][0] = fmaf(p1, va.x, acc1[i][0]);
                acc1[i][1] = fmaf(p1, va.y, acc1[i][1]);
                acc1[i][2] = fmaf(p1, va.z, acc1[i][2]);
                acc1[i][3] = fmaf(p1, va.w, acc1[i][3]);
                acc1[i][4] = fmaf(p1, vb.x, acc1[i][4]);
                acc1[i][5] = fmaf(p1, vb.y, acc1[i][5]);
                acc1[i][6] = fmaf(p1, vb.z, acc1[i][6]);
                acc1[i][7] = fmaf(p1, vb.w, acc1[i][7]);
            }
        }
    }

    // ---- combine branches, write O ----
    const float dw = dwp[0];
#pragma unroll
    for (int i = 0; i < 2; ++i) {
        float inv0 = 1.0f / l0v[i];
        float inv1 = dw   / l1v[i];
        float o[8];
#pragma unroll
        for (int j = 0; j < 8; ++j)
            o[j] = acc0[i][j] * inv0 - acc1[i][j] * inv1;
        float4* dst = (float4*)&O[base + (size_t)(q0 + r0 + i) * EDIM + hoff + tx * 8];
        dst[0] = make_float4(o[0], o[1], o[2], o[3]);
        dst[1] = make_float4(o[4], o[5], o[6], o[7]);
    }
}

// ------------------------------------------------------------------
// RMSNorm over the full E=1024 per (b,s) row, in place, * norm_w.
// ------------------------------------------------------------------
__global__ __launch_bounds__(256) void rmsnorm_kernel(
    float* __restrict__ O, const float* __restrict__ nw)
{
    const int row = blockIdx.x;           // 0..4095
    const int tid = threadIdx.x;
    float4 v = *(const float4*)&O[(size_t)row * EDIM + tid * 4];
    float ss = v.x * v.x + v.y * v.y + v.z * v.z + v.w * v.w;
    ss += __shfl_xor(ss, 1,  64);
    ss += __shfl_xor(ss, 2,  64);
    ss += __shfl_xor(ss, 4,  64);
    ss += __shfl_xor(ss, 8,  64);
    ss += __shfl_xor(ss, 16, 64);
    ss += __shfl_xor(ss, 32, 64);
    __shared__ float red[4];
    if ((tid & 63) == 0) red[tid >> 6] = ss;
    __syncthreads();
    float tot = red[0] + red[1] + red[2] + red[3];
    float rms = rsqrtf(tot * (1.0f / 1024.0f) + 1.1920929e-07f);
    float4 w = *(const float4*)&nw[tid * 4];
    v.x *= rms * w.x; v.y *= rms * w.y; v.z *= rms * w.z; v.w *= rms * w.w;
    *(float4*)&O[(size_t)row * EDIM + tid * 4] = v;
}

// ------------------------------------------------------------------
extern "C" void kernel_launch(void* const* d_in, const int* in_sizes, int n_in,
                              void* d_out, int out_size, void* d_ws, size_t ws_size,
                              hipStream_t stream)
{
    const float* x   = (const float*)d_in[0];
    const float* Wq  = (const float*)d_in[1];
    const float* Wk  = (const float*)d_in[2];
    const float* Wv  = (const float*)d_in[3];
    const float* nw  = (const float*)d_in[4];
    const float* Wo  = (const float*)d_in[5];
    const float* bo  = (const float*)d_in[6];
    const float* dwp = (const float*)d_in[7];
    float* out = (float*)d_out;

    const size_t NE = (size_t)GM * GN;   // 4096*1024
    float* Qb = (float*)d_ws;
    float* Kb = Qb + NE;
    float* Vb = Kb + NE;
    float* Ob = Vb + NE;

    // 1. QKV projections
    gemm_kernel<<<dim3(GN / BN, GM / BM, 3), 256, 0, stream>>>(
        x, Wq, Wk, Wv, Qb, Kb, Vb, nullptr, dwp, 0);
    // 2. diff flash attention
    attn_kernel<<<dim3(SDIM / BQ, 2 * HDIM), 256, 0, stream>>>(Qb, Kb, Vb, Ob, dwp);
    // 3. RMSNorm in place
    rmsnorm_kernel<<<4096, 256, 0, stream>>>(Ob, nw);
    // 4. output projection + bias, * (1-dw)
    gemm_kernel<<<dim3(GN / BN, GM / BM, 1), 256, 0, stream>>>(
        Ob, Wo, Wo, Wo, out, out, out, bo, dwp, 1);
}

// Round 2
// 744.150 us; speedup vs baseline: 1.9641x; 1.9641x over previous
//
#include <hip/hip_runtime.h>
#include <hip/hip_bf16.h>
#include <math.h>

// MultiHeadDiffAttention, MI355X. Round 2: MFMA bf16 attention.
// B=2 S=2048 E=1024 H=8 DH=128 F=64.
//   1. Q,K = x@W.T -> bf16 row-major; V -> bf16 TRANSPOSED Vt[bh][dh][s]
//   2. MFMA diff attention (16x16x32 bf16), no-max softmax, P via LDS fp32
//   3. RMSNorm fp32 in place
//   4. out = (O @ Wo.T + bo)*(1-dw)  fp32 VALU GEMM

#define SDIM 2048
#define EDIM 1024
#define HDIM 8
#define DHDIM 128

typedef unsigned short u16;
typedef __attribute__((ext_vector_type(8))) short bf16x8;
typedef __attribute__((ext_vector_type(8))) u16 u16x8;
typedef __attribute__((ext_vector_type(4))) float f32x4;

__device__ __forceinline__ u16 bf16rne(float f) {
    unsigned int u = __float_as_uint(f);
    u += 0x7fff + ((u >> 16) & 1);
    return (u16)(u >> 16);
}

// ------------------------------------------------------------------
// GEMM (fp32 math): C[M,N] = A[M,K] @ W[N,K]^T, M=4096 N=K=1024
// 128x128 block, BK=16, 256 threads, 8x8 micro-tile.
// ------------------------------------------------------------------
constexpr int GM = 4096, GN = 1024, GK = 1024;
constexpr int BM = 128, BN = 128, BK = 16;

// z=0 -> Qb (bf16 row), z=1 -> Kb (bf16 row), z=2 -> Vt (bf16 transposed)
__global__ __launch_bounds__(256) void gemm_qkv(
    const float* __restrict__ A,
    const float* __restrict__ W0, const float* __restrict__ W1, const float* __restrict__ W2,
    u16* __restrict__ Qb, u16* __restrict__ Kb, u16* __restrict__ Vtb)
{
    const int z = blockIdx.z;
    const float* W = (z == 0) ? W0 : ((z == 1) ? W1 : W2);

    __shared__ float As[BK][BM + 4];
    __shared__ float Bs[BK][BN + 4];

    const int tid = threadIdx.x;
    const int tx = tid & 15;
    const int ty = tid >> 4;
    const int m0 = blockIdx.y * BM;
    const int n0 = blockIdx.x * BN;

    float acc[8][8];
#pragma unroll
    for (int i = 0; i < 8; ++i)
#pragma unroll
        for (int j = 0; j < 8; ++j) acc[i][j] = 0.f;

    for (int k0 = 0; k0 < GK; k0 += BK) {
#pragma unroll
        for (int l = 0; l < 2; ++l) {
            int idx = tid + l * 256;
            int row = idx >> 2;
            int c4  = (idx & 3) << 2;
            float4 va = *(const float4*)&A[(size_t)(m0 + row) * GK + k0 + c4];
            As[c4 + 0][row] = va.x; As[c4 + 1][row] = va.y;
            As[c4 + 2][row] = va.z; As[c4 + 3][row] = va.w;
            float4 vb = *(const float4*)&W[(size_t)(n0 + row) * GK + k0 + c4];
            Bs[c4 + 0][row] = vb.x; Bs[c4 + 1][row] = vb.y;
            Bs[c4 + 2][row] = vb.z; Bs[c4 + 3][row] = vb.w;
        }
        __syncthreads();
#pragma unroll
        for (int kk = 0; kk < BK; ++kk) {
            float4 a0 = *(const float4*)&As[kk][ty * 8];
            float4 a1 = *(const float4*)&As[kk][ty * 8 + 4];
            float4 b0 = *(const float4*)&Bs[kk][tx * 8];
            float4 b1 = *(const float4*)&Bs[kk][tx * 8 + 4];
            float a[8] = {a0.x, a0.y, a0.z, a0.w, a1.x, a1.y, a1.z, a1.w};
            float b[8] = {b0.x, b0.y, b0.z, b0.w, b1.x, b1.y, b1.z, b1.w};
#pragma unroll
            for (int i = 0; i < 8; ++i)
#pragma unroll
                for (int j = 0; j < 8; ++j)
                    acc[i][j] = fmaf(a[i], b[j], acc[i][j]);
        }
        __syncthreads();
    }

    if (z < 2) {
        u16* C = (z == 0) ? Qb : Kb;
#pragma unroll
        for (int i = 0; i < 8; ++i) {
            u16x8 pk;
#pragma unroll
            for (int j = 0; j < 8; ++j) pk[j] = bf16rne(acc[i][j]);
            *(u16x8*)&C[(size_t)(m0 + ty * 8 + i) * GN + n0 + tx * 8] = pk;
        }
    } else {
        // transposed store: Vt[(b*8+h)*128+dh][s], s contiguous
        const int bb = m0 >> 11;              // 2048 rows per batch
        const int ss = (m0 & 2047) + ty * 8;
#pragma unroll
        for (int j = 0; j < 8; ++j) {
            int dhg = n0 + tx * 8 + j;        // global feature 0..1023
            int hh  = dhg >> 7;
            int dh  = dhg & 127;
            u16x8 pk;
#pragma unroll
            for (int i = 0; i < 8; ++i) pk[i] = bf16rne(acc[i][j]);
            *(u16x8*)&Vtb[((size_t)(bb * 8 + hh) * DHDIM + dh) * SDIM + ss] = pk;
        }
    }
}

// fp32 output GEMM for the final projection (+bias, *(1-dw))
__global__ __launch_bounds__(256) void gemm_out(
    const float* __restrict__ A, const float* __restrict__ W,
    float* __restrict__ C, const float* __restrict__ bias,
    const float* __restrict__ dwp)
{
    __shared__ float As[BK][BM + 4];
    __shared__ float Bs[BK][BN + 4];

    const int tid = threadIdx.x;
    const int tx = tid & 15;
    const int ty = tid >> 4;
    const int m0 = blockIdx.y * BM;
    const int n0 = blockIdx.x * BN;

    float acc[8][8];
#pragma unroll
    for (int i = 0; i < 8; ++i)
#pragma unroll
        for (int j = 0; j < 8; ++j) acc[i][j] = 0.f;

    for (int k0 = 0; k0 < GK; k0 += BK) {
#pragma unroll
        for (int l = 0; l < 2; ++l) {
            int idx = tid + l * 256;
            int row = idx >> 2;
            int c4  = (idx & 3) << 2;
            float4 va = *(const float4*)&A[(size_t)(m0 + row) * GK + k0 + c4];
            As[c4 + 0][row] = va.x; As[c4 + 1][row] = va.y;
            As[c4 + 2][row] = va.z; As[c4 + 3][row] = va.w;
            float4 vb = *(const float4*)&W[(size_t)(n0 + row) * GK + k0 + c4];
            Bs[c4 + 0][row] = vb.x; Bs[c4 + 1][row] = vb.y;
            Bs[c4 + 2][row] = vb.z; Bs[c4 + 3][row] = vb.w;
        }
        __syncthreads();
#pragma unroll
        for (int kk = 0; kk < BK; ++kk) {
            float4 a0 = *(const float4*)&As[kk][ty * 8];
            float4 a1 = *(const float4*)&As[kk][ty * 8 + 4];
            float4 b0 = *(const float4*)&Bs[kk][tx * 8];
            float4 b1 = *(const float4*)&Bs[kk][tx * 8 + 4];
            float a[8] = {a0.x, a0.y, a0.z, a0.w, a1.x, a1.y, a1.z, a1.w};
            float b[8] = {b0.x, b0.y, b0.z, b0.w, b1.x, b1.y, b1.z, b1.w};
#pragma unroll
            for (int i = 0; i < 8; ++i)
#pragma unroll
                for (int j = 0; j < 8; ++j)
                    acc[i][j] = fmaf(a[i], b[j], acc[i][j]);
        }
        __syncthreads();
    }

    const float scale = 1.0f - dwp[0];
    float bv[8];
#pragma unroll
    for (int j = 0; j < 8; ++j) bv[j] = bias[n0 + tx * 8 + j];
#pragma unroll
    for (int i = 0; i < 8; ++i) {
        float o[8];
#pragma unroll
        for (int j = 0; j < 8; ++j) o[j] = (acc[i][j] + bv[j]) * scale;
        float4* dst = (float4*)&C[(size_t)(m0 + ty * 8 + i) * GN + n0 + tx * 8];
        dst[0] = make_float4(o[0], o[1], o[2], o[3]);
        dst[1] = make_float4(o[4], o[5], o[6], o[7]);
    }
}

// ------------------------------------------------------------------
// MFMA diff attention. One wave (64 thr) per block; wave owns 16 q rows.
// Grid: (S/16, B*H). BKV=32 per iteration.
// Fragment layouts (16x16x32 bf16, measured m89/m120):
//   A[m=lane&15][k=quad*8+j]   B[n=lane&15][k=quad*8+j]
//   C/D: row=quad*4+reg, col=lane&15
// No-max softmax: p = exp2(s*scale*log2e), l = sum p  (scores ~N(0,1),
// |s| <= |q||k|/8 ~ 18 max -> exp2 safe in fp32).
// ------------------------------------------------------------------
__global__ __launch_bounds__(64) void attn_mfma(
    const u16* __restrict__ Qb, const u16* __restrict__ Kb,
    const u16* __restrict__ Vtb, float* __restrict__ O,
    const float* __restrict__ dwp)
{
    const int lane = threadIdx.x & 63;
    const int ln   = lane & 15;
    const int quad = lane >> 4;
    const int bh = blockIdx.y, b = bh >> 3, h = bh & 7;
    const int q0 = blockIdx.x * 16;

    const size_t qk_off = (size_t)b * SDIM * EDIM + h * DHDIM;
    const u16* qp = Qb + qk_off + (size_t)(q0 + ln) * EDIM + quad * 8;
    bf16x8 aq[2][2];
    aq[0][0] = *(const bf16x8*)(qp);
    aq[0][1] = *(const bf16x8*)(qp + 32);
    aq[1][0] = *(const bf16x8*)(qp + 64);
    aq[1][1] = *(const bf16x8*)(qp + 96);

    __shared__ float Pl[2][16][36];   // [branch][q row][kv col], pad 36

    f32x4 acc0[8], acc1[8];           // [dh_tile], rows=q, col=dh
#pragma unroll
    for (int d = 0; d < 8; ++d) {
        acc0[d] = (f32x4){0.f, 0.f, 0.f, 0.f};
        acc1[d] = (f32x4){0.f, 0.f, 0.f, 0.f};
    }
    f32x4 lsum0 = (f32x4){0.f, 0.f, 0.f, 0.f};
    f32x4 lsum1 = (f32x4){0.f, 0.f, 0.f, 0.f};

    const float C = 0.125f * 1.44269504f;    // scale * log2(e)
    const f32x4 z4 = (f32x4){0.f, 0.f, 0.f, 0.f};

    const u16* kbase = Kb + qk_off;
    const u16* vbase = Vtb + (size_t)bh * DHDIM * SDIM + (size_t)ln * SDIM;

    for (int kv0 = 0; kv0 < SDIM; kv0 += 32) {
        // ---- K fragments: rows kv0+nt*16+ln, features br*64+kb*32+quad*8 ----
        const u16* kp0 = kbase + (size_t)(kv0 + ln) * EDIM + quad * 8;
        const u16* kp1 = kp0 + 16 * EDIM;
        bf16x8 k000 = *(const bf16x8*)(kp0);
        bf16x8 k001 = *(const bf16x8*)(kp0 + 32);
        bf16x8 k100 = *(const bf16x8*)(kp0 + 64);
        bf16x8 k101 = *(const bf16x8*)(kp0 + 96);
        bf16x8 k010 = *(const bf16x8*)(kp1);
        bf16x8 k011 = *(const bf16x8*)(kp1 + 32);
        bf16x8 k110 = *(const bf16x8*)(kp1 + 64);
        bf16x8 k111 = *(const bf16x8*)(kp1 + 96);

        // ---- V fragments: Vt rows dt*16+ln, kv cols kv0+quad*8 ----
        bf16x8 bv[8];
        const u16* vp = vbase + kv0 + quad * 8;
#pragma unroll
        for (int dt = 0; dt < 8; ++dt)
            bv[dt] = *(const bf16x8*)(vp + (size_t)dt * 16 * SDIM);

        // ---- QK^T: s[branch][nt] ----
        f32x4 s00 = __builtin_amdgcn_mfma_f32_16x16x32_bf16(aq[0][0], k000, z4, 0, 0, 0);
        s00 = __builtin_amdgcn_mfma_f32_16x16x32_bf16(aq[0][1], k001, s00, 0, 0, 0);
        f32x4 s01 = __builtin_amdgcn_mfma_f32_16x16x32_bf16(aq[0][0], k010, z4, 0, 0, 0);
        s01 = __builtin_amdgcn_mfma_f32_16x16x32_bf16(aq[0][1], k011, s01, 0, 0, 0);
        f32x4 s10 = __builtin_amdgcn_mfma_f32_16x16x32_bf16(aq[1][0], k100, z4, 0, 0, 0);
        s10 = __builtin_amdgcn_mfma_f32_16x16x32_bf16(aq[1][1], k101, s10, 0, 0, 0);
        f32x4 s11 = __builtin_amdgcn_mfma_f32_16x16x32_bf16(aq[1][0], k110, z4, 0, 0, 0);
        s11 = __builtin_amdgcn_mfma_f32_16x16x32_bf16(aq[1][1], k111, s11, 0, 0, 0);

        __syncthreads();   // WAR: previous iteration's P reads complete
#pragma unroll
        for (int r = 0; r < 4; ++r) {
            float p;
            p = exp2f(s00[r] * C); lsum0[r] += p; Pl[0][quad * 4 + r][ln]      = p;
            p = exp2f(s01[r] * C); lsum0[r] += p; Pl[0][quad * 4 + r][16 + ln] = p;
            p = exp2f(s10[r] * C); lsum1[r] += p; Pl[1][quad * 4 + r][ln]      = p;
            p = exp2f(s11[r] * C); lsum1[r] += p; Pl[1][quad * 4 + r][16 + ln] = p;
        }
        __syncthreads();   // RAW: P visible across lanes

        // ---- read P as A-fragment (q row = ln, kv = quad*8+j), cvt bf16 ----
        bf16x8 ap0, ap1;
        {
            const float* pr0 = &Pl[0][ln][quad * 8];
            f32x4 lo = *(const f32x4*)pr0;
            f32x4 hi = *(const f32x4*)(pr0 + 4);
#pragma unroll
            for (int j = 0; j < 4; ++j) { ap0[j] = (short)bf16rne(lo[j]); ap0[4 + j] = (short)bf16rne(hi[j]); }
            const float* pr1 = &Pl[1][ln][quad * 8];
            f32x4 lo1 = *(const f32x4*)pr1;
            f32x4 hi1 = *(const f32x4*)(pr1 + 4);
#pragma unroll
            for (int j = 0; j < 4; ++j) { ap1[j] = (short)bf16rne(lo1[j]); ap1[4 + j] = (short)bf16rne(hi1[j]); }
        }

        // ---- PV: acc[dh_tile] += P * Vt^T ----
#pragma unroll
        for (int dt = 0; dt < 8; ++dt) {
            acc0[dt] = __builtin_amdgcn_mfma_f32_16x16x32_bf16(ap0, bv[dt], acc0[dt], 0, 0, 0);
            acc1[dt] = __builtin_amdgcn_mfma_f32_16x16x32_bf16(ap1, bv[dt], acc1[dt], 0, 0, 0);
        }
    }

    // ---- reduce l over the 16 cols (lanes within quad) ----
#pragma unroll
    for (int r = 0; r < 4; ++r) {
        float v0 = lsum0[r], v1 = lsum1[r];
        v0 += __shfl_xor(v0, 1, 16); v1 += __shfl_xor(v1, 1, 16);
        v0 += __shfl_xor(v0, 2, 16); v1 += __shfl_xor(v1, 2, 16);
        v0 += __shfl_xor(v0, 4, 16); v1 += __shfl_xor(v1, 4, 16);
        v0 += __shfl_xor(v0, 8, 16); v1 += __shfl_xor(v1, 8, 16);
        lsum0[r] = v0; lsum1[r] = v1;
    }

    const float dw = dwp[0];
    float* ob = O + (size_t)b * SDIM * EDIM + (size_t)h * DHDIM;
#pragma unroll
    for (int r = 0; r < 4; ++r) {
        float inv0 = 1.0f / lsum0[r];
        float inv1 = dw / lsum1[r];
        float* orow = ob + (size_t)(q0 + quad * 4 + r) * EDIM + ln;
#pragma unroll
        for (int dt = 0; dt < 8; ++dt)
            orow[dt * 16] = acc0[dt][r] * inv0 - acc1[dt][r] * inv1;
    }
}

// ------------------------------------------------------------------
// RMSNorm over E=1024 per (b,s), in place.
// ------------------------------------------------------------------
__global__ __launch_bounds__(256) void rmsnorm_kernel(
    float* __restrict__ O, const float* __restrict__ nw)
{
    const int row = blockIdx.x;
    const int tid = threadIdx.x;
    float4 v = *(const float4*)&O[(size_t)row * EDIM + tid * 4];
    float ss = v.x * v.x + v.y * v.y + v.z * v.z + v.w * v.w;
    ss += __shfl_xor(ss, 1,  64);
    ss += __shfl_xor(ss, 2,  64);
    ss += __shfl_xor(ss, 4,  64);
    ss += __shfl_xor(ss, 8,  64);
    ss += __shfl_xor(ss, 16, 64);
    ss += __shfl_xor(ss, 32, 64);
    __shared__ float red[4];
    if ((tid & 63) == 0) red[tid >> 6] = ss;
    __syncthreads();
    float tot = red[0] + red[1] + red[2] + red[3];
    float rms = rsqrtf(tot * (1.0f / 1024.0f) + 1.1920929e-07f);
    float4 w = *(const float4*)&nw[tid * 4];
    v.x *= rms * w.x; v.y *= rms * w.y; v.z *= rms * w.z; v.w *= rms * w.w;
    *(float4*)&O[(size_t)row * EDIM + tid * 4] = v;
}

// ------------------------------------------------------------------
extern "C" void kernel_launch(void* const* d_in, const int* in_sizes, int n_in,
                              void* d_out, int out_size, void* d_ws, size_t ws_size,
                              hipStream_t stream)
{
    const float* x   = (const float*)d_in[0];
    const float* Wq  = (const float*)d_in[1];
    const float* Wk  = (const float*)d_in[2];
    const float* Wv  = (const float*)d_in[3];
    const float* nw  = (const float*)d_in[4];
    const float* Wo  = (const float*)d_in[5];
    const float* bo  = (const float*)d_in[6];
    const float* dwp = (const float*)d_in[7];
    float* out = (float*)d_out;

    const size_t NE = (size_t)GM * GN;   // 4096*1024
    u16* Qb  = (u16*)d_ws;
    u16* Kb  = Qb + NE;
    u16* Vtb = Kb + NE;
    float* Ob = (float*)(Vtb + NE);      // 24 MB offset, 16B aligned

    // 1. QKV projections -> bf16 (V transposed)
    gemm_qkv<<<dim3(GN / BN, GM / BM, 3), 256, 0, stream>>>(
        x, Wq, Wk, Wv, Qb, Kb, Vtb);
    // 2. MFMA diff attention
    attn_mfma<<<dim3(SDIM / 16, 2 * HDIM), 64, 0, stream>>>(Qb, Kb, Vtb, Ob, dwp);
    // 3. RMSNorm in place
    rmsnorm_kernel<<<4096, 256, 0, stream>>>(Ob, nw);
    // 4. output projection
    gemm_out<<<dim3(GN / BN, GM / BM, 1), 256, 0, stream>>>(Ob, Wo, out, bo, dwp);
}

// Round 3
// 391.864 us; speedup vs baseline: 3.7298x; 1.8990x over previous
//
#include <hip/hip_runtime.h>
#include <hip/hip_bf16.h>
#include <math.h>

// MultiHeadDiffAttention, MI355X. Round 3: bf16 MFMA projection GEMMs.
// B=2 S=2048 E=1024 H=8 DH=128 F=64.
//   0. cast x, Wq, Wk, Wv, Wo -> bf16
//   1. Q,K = x@W.T bf16 row-major; V -> bf16 transposed Vt[bh][dh][s]
//      (m97-style MFMA GEMM: 128x128 tile, BK=32, global_load_lds w=16,
//       chunk-XOR swizzle for conflict-free ds_read_b128)
//   2. MFMA diff attention (16x16x32 bf16), no-max softmax
//   3. RMSNorm fp32 -> bf16 normed
//   4. out = (normed @ Wo.T + bo)*(1-dw)  bf16 MFMA GEMM, fp32 out

#define SDIM 2048
#define EDIM 1024
#define HDIM 8
#define DHDIM 128

typedef unsigned short u16;
typedef __attribute__((ext_vector_type(8))) short bf16x8;
typedef __attribute__((ext_vector_type(4))) u16 u16x4;
typedef __attribute__((ext_vector_type(8))) u16 u16x8;
typedef __attribute__((ext_vector_type(4))) float f32x4;

__device__ __forceinline__ u16 bf16rne(float f) {
    unsigned int u = __float_as_uint(f);
    u += 0x7fff + ((u >> 16) & 1);
    return (u16)(u >> 16);
}

__device__ __forceinline__ void gload16(void* lds, const void* g) {
    __builtin_amdgcn_global_load_lds(
        (const __attribute__((address_space(1))) unsigned int*)g,
        (__attribute__((address_space(3))) unsigned int*)lds, 16, 0, 0);
}

constexpr int GM = 4096, GN = 1024, GK = 1024;

// ------------------------------------------------------------------
// cast fp32 -> bf16: x (4M) + Wq/Wk/Wv/Wo (1M each). 8 elems/thread.
// grid.x = 2048 + 4*512 = 4096 blocks of 256.
// ------------------------------------------------------------------
__global__ __launch_bounds__(256) void cast_bf16(
    const float* __restrict__ x,  const float* __restrict__ wq,
    const float* __restrict__ wk, const float* __restrict__ wv,
    const float* __restrict__ wo,
    u16* __restrict__ xb,  u16* __restrict__ wqb, u16* __restrict__ wkb,
    u16* __restrict__ wvb, u16* __restrict__ wob)
{
    int bid = blockIdx.x;
    const float* src; u16* dst; int lb;
    if (bid < 2048)      { src = x;  dst = xb;  lb = bid; }
    else if (bid < 2560) { src = wq; dst = wqb; lb = bid - 2048; }
    else if (bid < 3072) { src = wk; dst = wkb; lb = bid - 2560; }
    else if (bid < 3584) { src = wv; dst = wvb; lb = bid - 3072; }
    else                 { src = wo; dst = wob; lb = bid - 3584; }
    size_t i = ((size_t)lb * 256 + threadIdx.x) * 8;
    float4 a = *(const float4*)&src[i];
    float4 b = *(const float4*)&src[i + 4];
    u16x8 o;
    o[0] = bf16rne(a.x); o[1] = bf16rne(a.y); o[2] = bf16rne(a.z); o[3] = bf16rne(a.w);
    o[4] = bf16rne(b.x); o[5] = bf16rne(b.y); o[6] = bf16rne(b.z); o[7] = bf16rne(b.w);
    *(u16x8*)&dst[i] = o;
}

// ------------------------------------------------------------------
// bf16 MFMA GEMM core: C[M,N] = A[M,K] @ W[N,K]^T, 128x128 tile, BK=32.
// 256 thr = 4 waves, each wave 64x64 (4x4 fragments of 16x16).
// LDS chunk swizzle: global 16B-chunk kc of row r lives at lds chunk
// kc ^ ((r>>1)&3)  -> conflict-free ds_read_b128.
// acc[i][j][r] = C[m0 + wm + i*16 + quad*4 + r][n0 + wn + j*16 + ln]
// ------------------------------------------------------------------
struct GemmCore {
    f32x4 acc[4][4];
    int m0, n0, wm, wn, ln, quad;
};

__device__ __forceinline__ void gemm_core(
    GemmCore& g, const u16* __restrict__ A, const u16* __restrict__ W,
    u16* AsBase, u16* BsBase)
{
    const int tid = threadIdx.x;
    const int lane = tid & 63;
    const int wv = tid >> 6;
    g.ln = lane & 15; g.quad = lane >> 4;
    g.wm = (wv >> 1) * 64; g.wn = (wv & 1) * 64;
    g.m0 = blockIdx.y * 128; g.n0 = blockIdx.x * 128;

#pragma unroll
    for (int i = 0; i < 4; ++i)
#pragma unroll
        for (int j = 0; j < 4; ++j)
            g.acc[i][j] = (f32x4){0.f, 0.f, 0.f, 0.f};

    // staging map (constant): slot s -> row s>>2, lds chunk s&3,
    // global chunk (s&3)^((row>>1)&3)
    const int s0 = tid, s1 = tid + 256;
    const int ar0 = s0 >> 2, ac0 = (((s0 & 3) ^ ((ar0 >> 1) & 3)) * 8);
    const int ar1 = s1 >> 2, ac1 = (((s1 & 3) ^ ((ar1 >> 1) & 3)) * 8);
    const u16* pa0 = A + (size_t)(g.m0 + ar0) * GK + ac0;
    const u16* pa1 = A + (size_t)(g.m0 + ar1) * GK + ac1;
    const u16* pb0 = W + (size_t)(g.n0 + ar0) * GK + ac0;
    const u16* pb1 = W + (size_t)(g.n0 + ar1) * GK + ac1;
    u16* la0 = AsBase + s0 * 8; u16* la1 = AsBase + s1 * 8;
    u16* lb0 = BsBase + s0 * 8; u16* lb1 = BsBase + s1 * 8;

    const int roff = ((g.quad ^ ((g.ln >> 1) & 3)) * 8);

    for (int k0 = 0; k0 < GK; k0 += 32) {
        gload16(la0, pa0 + k0);
        gload16(la1, pa1 + k0);
        gload16(lb0, pb0 + k0);
        gload16(lb1, pb1 + k0);
        __syncthreads();           // drains vmcnt before barrier

        bf16x8 af[4], bfr[4];
#pragma unroll
        for (int t = 0; t < 4; ++t) {
            af[t]  = *(const bf16x8*)&AsBase[(g.wm + t * 16 + g.ln) * 32 + roff];
            bfr[t] = *(const bf16x8*)&BsBase[(g.wn + t * 16 + g.ln) * 32 + roff];
        }
#pragma unroll
        for (int i = 0; i < 4; ++i)
#pragma unroll
            for (int j = 0; j < 4; ++j)
                g.acc[i][j] = __builtin_amdgcn_mfma_f32_16x16x32_bf16(
                    af[i], bfr[j], g.acc[i][j], 0, 0, 0);
        __syncthreads();           // all reads done before next overwrite
    }
}

// z=0 -> Qb (bf16 row), z=1 -> Kb, z=2 -> Vt transposed [bh][dh][s]
__global__ __launch_bounds__(256) void gemm_qkv(
    const u16* __restrict__ A,
    const u16* __restrict__ W0, const u16* __restrict__ W1, const u16* __restrict__ W2,
    u16* __restrict__ Qb, u16* __restrict__ Kb, u16* __restrict__ Vtb)
{
    __shared__ u16 As[128 * 32];
    __shared__ u16 Bs[128 * 32];
    const int z = blockIdx.z;
    const u16* W = (z == 0) ? W0 : ((z == 1) ? W1 : W2);
    GemmCore g;
    gemm_core(g, A, W, As, Bs);

    if (z < 2) {
        u16* C = (z == 0) ? Qb : Kb;
#pragma unroll
        for (int i = 0; i < 4; ++i) {
            int rb = g.m0 + g.wm + i * 16 + g.quad * 4;
#pragma unroll
            for (int r = 0; r < 4; ++r) {
                u16* crow = C + (size_t)(rb + r) * GN + g.n0 + g.wn + g.ln;
#pragma unroll
                for (int j = 0; j < 4; ++j)
                    crow[j * 16] = bf16rne(g.acc[i][j][r]);
            }
        }
    } else {
        // Vt[(b*8+h)*128+dh][s], s contiguous; 4 consecutive s per u16x4
        const int bb = g.m0 >> 11;
        const int sb = (g.m0 & 2047) + g.wm + g.quad * 4;
#pragma unroll
        for (int j = 0; j < 4; ++j) {
            int dhg = g.n0 + g.wn + j * 16 + g.ln;
            int hh = dhg >> 7, dh = dhg & 127;
            u16* vrow = Vtb + ((size_t)(bb * 8 + hh) * DHDIM + dh) * SDIM + sb;
#pragma unroll
            for (int i = 0; i < 4; ++i) {
                u16x4 pk;
#pragma unroll
                for (int r = 0; r < 4; ++r) pk[r] = bf16rne(g.acc[i][j][r]);
                *(u16x4*)&vrow[i * 16] = pk;
            }
        }
    }
}

// out = (A @ W.T + bias) * (1-dw), fp32 output
__global__ __launch_bounds__(256) void gemm_out(
    const u16* __restrict__ A, const u16* __restrict__ W,
    float* __restrict__ C, const float* __restrict__ bias,
    const float* __restrict__ dwp)
{
    __shared__ u16 As[128 * 32];
    __shared__ u16 Bs[128 * 32];
    GemmCore g;
    gemm_core(g, A, W, As, Bs);

    const float scale = 1.0f - dwp[0];
    float bv[4];
#pragma unroll
    for (int j = 0; j < 4; ++j) bv[j] = bias[g.n0 + g.wn + j * 16 + g.ln];
#pragma unroll
    for (int i = 0; i < 4; ++i) {
        int rb = g.m0 + g.wm + i * 16 + g.quad * 4;
#pragma unroll
        for (int r = 0; r < 4; ++r) {
            float* crow = C + (size_t)(rb + r) * GN + g.n0 + g.wn + g.ln;
#pragma unroll
            for (int j = 0; j < 4; ++j)
                crow[j * 16] = (g.acc[i][j][r] + bv[j]) * scale;
        }
    }
}

// ------------------------------------------------------------------
// MFMA diff attention (unchanged from R2). One wave per block, 16 q rows.
// ------------------------------------------------------------------
__global__ __launch_bounds__(64) void attn_mfma(
    const u16* __restrict__ Qb, const u16* __restrict__ Kb,
    const u16* __restrict__ Vtb, float* __restrict__ O,
    const float* __restrict__ dwp)
{
    const int lane = threadIdx.x & 63;
    const int ln   = lane & 15;
    const int quad = lane >> 4;
    const int bh = blockIdx.y, b = bh >> 3, h = bh & 7;
    const int q0 = blockIdx.x * 16;

    const size_t qk_off = (size_t)b * SDIM * EDIM + h * DHDIM;
    const u16* qp = Qb + qk_off + (size_t)(q0 + ln) * EDIM + quad * 8;
    bf16x8 aq[2][2];
    aq[0][0] = *(const bf16x8*)(qp);
    aq[0][1] = *(const bf16x8*)(qp + 32);
    aq[1][0] = *(const bf16x8*)(qp + 64);
    aq[1][1] = *(const bf16x8*)(qp + 96);

    __shared__ float Pl[2][16][36];

    f32x4 acc0[8], acc1[8];
#pragma unroll
    for (int d = 0; d < 8; ++d) {
        acc0[d] = (f32x4){0.f, 0.f, 0.f, 0.f};
        acc1[d] = (f32x4){0.f, 0.f, 0.f, 0.f};
    }
    f32x4 lsum0 = (f32x4){0.f, 0.f, 0.f, 0.f};
    f32x4 lsum1 = (f32x4){0.f, 0.f, 0.f, 0.f};

    const float C = 0.125f * 1.44269504f;
    const f32x4 z4 = (f32x4){0.f, 0.f, 0.f, 0.f};

    const u16* kbase = Kb + qk_off;
    const u16* vbase = Vtb + (size_t)bh * DHDIM * SDIM + (size_t)ln * SDIM;

    for (int kv0 = 0; kv0 < SDIM; kv0 += 32) {
        const u16* kp0 = kbase + (size_t)(kv0 + ln) * EDIM + quad * 8;
        const u16* kp1 = kp0 + 16 * EDIM;
        bf16x8 k000 = *(const bf16x8*)(kp0);
        bf16x8 k001 = *(const bf16x8*)(kp0 + 32);
        bf16x8 k100 = *(const bf16x8*)(kp0 + 64);
        bf16x8 k101 = *(const bf16x8*)(kp0 + 96);
        bf16x8 k010 = *(const bf16x8*)(kp1);
        bf16x8 k011 = *(const bf16x8*)(kp1 + 32);
        bf16x8 k110 = *(const bf16x8*)(kp1 + 64);
        bf16x8 k111 = *(const bf16x8*)(kp1 + 96);

        bf16x8 bv[8];
        const u16* vp = vbase + kv0 + quad * 8;
#pragma unroll
        for (int dt = 0; dt < 8; ++dt)
            bv[dt] = *(const bf16x8*)(vp + (size_t)dt * 16 * SDIM);

        f32x4 s00 = __builtin_amdgcn_mfma_f32_16x16x32_bf16(aq[0][0], k000, z4, 0, 0, 0);
        s00 = __builtin_amdgcn_mfma_f32_16x16x32_bf16(aq[0][1], k001, s00, 0, 0, 0);
        f32x4 s01 = __builtin_amdgcn_mfma_f32_16x16x32_bf16(aq[0][0], k010, z4, 0, 0, 0);
        s01 = __builtin_amdgcn_mfma_f32_16x16x32_bf16(aq[0][1], k011, s01, 0, 0, 0);
        f32x4 s10 = __builtin_amdgcn_mfma_f32_16x16x32_bf16(aq[1][0], k100, z4, 0, 0, 0);
        s10 = __builtin_amdgcn_mfma_f32_16x16x32_bf16(aq[1][1], k101, s10, 0, 0, 0);
        f32x4 s11 = __builtin_amdgcn_mfma_f32_16x16x32_bf16(aq[1][0], k110, z4, 0, 0, 0);
        s11 = __builtin_amdgcn_mfma_f32_16x16x32_bf16(aq[1][1], k111, s11, 0, 0, 0);

        __syncthreads();
#pragma unroll
        for (int r = 0; r < 4; ++r) {
            float p;
            p = exp2f(s00[r] * C); lsum0[r] += p; Pl[0][quad * 4 + r][ln]      = p;
            p = exp2f(s01[r] * C); lsum0[r] += p; Pl[0][quad * 4 + r][16 + ln] = p;
            p = exp2f(s10[r] * C); lsum1[r] += p; Pl[1][quad * 4 + r][ln]      = p;
            p = exp2f(s11[r] * C); lsum1[r] += p; Pl[1][quad * 4 + r][16 + ln] = p;
        }
        __syncthreads();

        bf16x8 ap0, ap1;
        {
            const float* pr0 = &Pl[0][ln][quad * 8];
            f32x4 lo = *(const f32x4*)pr0;
            f32x4 hi = *(const f32x4*)(pr0 + 4);
#pragma unroll
            for (int j = 0; j < 4; ++j) { ap0[j] = (short)bf16rne(lo[j]); ap0[4 + j] = (short)bf16rne(hi[j]); }
            const float* pr1 = &Pl[1][ln][quad * 8];
            f32x4 lo1 = *(const f32x4*)pr1;
            f32x4 hi1 = *(const f32x4*)(pr1 + 4);
#pragma unroll
            for (int j = 0; j < 4; ++j) { ap1[j] = (short)bf16rne(lo1[j]); ap1[4 + j] = (short)bf16rne(hi1[j]); }
        }

#pragma unroll
        for (int dt = 0; dt < 8; ++dt) {
            acc0[dt] = __builtin_amdgcn_mfma_f32_16x16x32_bf16(ap0, bv[dt], acc0[dt], 0, 0, 0);
            acc1[dt] = __builtin_amdgcn_mfma_f32_16x16x32_bf16(ap1, bv[dt], acc1[dt], 0, 0, 0);
        }
    }

#pragma unroll
    for (int r = 0; r < 4; ++r) {
        float v0 = lsum0[r], v1 = lsum1[r];
        v0 += __shfl_xor(v0, 1, 16); v1 += __shfl_xor(v1, 1, 16);
        v0 += __shfl_xor(v0, 2, 16); v1 += __shfl_xor(v1, 2, 16);
        v0 += __shfl_xor(v0, 4, 16); v1 += __shfl_xor(v1, 4, 16);
        v0 += __shfl_xor(v0, 8, 16); v1 += __shfl_xor(v1, 8, 16);
        lsum0[r] = v0; lsum1[r] = v1;
    }

    const float dw = dwp[0];
    float* ob = O + (size_t)b * SDIM * EDIM + (size_t)h * DHDIM;
#pragma unroll
    for (int r = 0; r < 4; ++r) {
        float inv0 = 1.0f / lsum0[r];
        float inv1 = dw / lsum1[r];
        float* orow = ob + (size_t)(q0 + quad * 4 + r) * EDIM + ln;
#pragma unroll
        for (int dt = 0; dt < 8; ++dt)
            orow[dt * 16] = acc0[dt][r] * inv0 - acc1[dt][r] * inv1;
    }
}

// ------------------------------------------------------------------
// RMSNorm over E=1024 per (b,s): fp32 in -> bf16 normed out.
// ------------------------------------------------------------------
__global__ __launch_bounds__(256) void rmsnorm_kernel(
    const float* __restrict__ O, const float* __restrict__ nw,
    u16* __restrict__ Nb)
{
    const int row = blockIdx.x;
    const int tid = threadIdx.x;
    float4 v = *(const float4*)&O[(size_t)row * EDIM + tid * 4];
    float ss = v.x * v.x + v.y * v.y + v.z * v.z + v.w * v.w;
    ss += __shfl_xor(ss, 1,  64);
    ss += __shfl_xor(ss, 2,  64);
    ss += __shfl_xor(ss, 4,  64);
    ss += __shfl_xor(ss, 8,  64);
    ss += __shfl_xor(ss, 16, 64);
    ss += __shfl_xor(ss, 32, 64);
    __shared__ float red[4];
    if ((tid & 63) == 0) red[tid >> 6] = ss;
    __syncthreads();
    float tot = red[0] + red[1] + red[2] + red[3];
    float rms = rsqrtf(tot * (1.0f / 1024.0f) + 1.1920929e-07f);
    float4 w = *(const float4*)&nw[tid * 4];
    u16x4 o;
    o[0] = bf16rne(v.x * rms * w.x);
    o[1] = bf16rne(v.y * rms * w.y);
    o[2] = bf16rne(v.z * rms * w.z);
    o[3] = bf16rne(v.w * rms * w.w);
    *(u16x4*)&Nb[(size_t)row * EDIM + tid * 4] = o;
}

// ------------------------------------------------------------------
extern "C" void kernel_launch(void* const* d_in, const int* in_sizes, int n_in,
                              void* d_out, int out_size, void* d_ws, size_t ws_size,
                              hipStream_t stream)
{
    const float* x   = (const float*)d_in[0];
    const float* Wq  = (const float*)d_in[1];
    const float* Wk  = (const float*)d_in[2];
    const float* Wv  = (const float*)d_in[3];
    const float* nw  = (const float*)d_in[4];
    const float* Wo  = (const float*)d_in[5];
    const float* bo  = (const float*)d_in[6];
    const float* dwp = (const float*)d_in[7];
    float* out = (float*)d_out;

    const size_t NE = (size_t)GM * GN;       // 4096*1024
    const size_t WE = (size_t)GN * GK;       // 1024*1024
    u16* xb  = (u16*)d_ws;                   // 8 MB (reused as Nb later)
    u16* wqb = xb + NE;                      // 2 MB
    u16* wkb = wqb + WE;
    u16* wvb = wkb + WE;
    u16* wob = wvb + WE;
    u16* Qb  = wob + WE;                     // 8 MB
    u16* Kb  = Qb + NE;
    u16* Vtb = Kb + NE;
    float* Ob = (float*)(Vtb + NE);          // 16 MB fp32
    u16* Nb  = xb;                           // overlay: xb dead after gemm_qkv

    // 0. casts
    cast_bf16<<<4096, 256, 0, stream>>>(x, Wq, Wk, Wv, Wo,
                                        xb, wqb, wkb, wvb, wob);
    // 1. QKV projections (bf16 MFMA)
    gemm_qkv<<<dim3(GN / 128, GM / 128, 3), 256, 0, stream>>>(
        xb, wqb, wkb, wvb, Qb, Kb, Vtb);
    // 2. MFMA diff attention
    attn_mfma<<<dim3(SDIM / 16, 2 * HDIM), 64, 0, stream>>>(Qb, Kb, Vtb, Ob, dwp);
    // 3. RMSNorm -> bf16
    rmsnorm_kernel<<<4096, 256, 0, stream>>>(Ob, nw, Nb);
    // 4. output projection (bf16 MFMA)
    gemm_out<<<dim3(GN / 128, GM / 128, 1), 256, 0, stream>>>(
        Nb, wob, out, bo, dwp);
}

// Round 4
// 312.372 us; speedup vs baseline: 4.6789x; 1.2545x over previous
//
#include <hip/hip_runtime.h>
#include <hip/hip_bf16.h>
#include <math.h>

// MultiHeadDiffAttention, MI355X. Round 4: 4-wave LDS-shared attention,
// KV-split x2 with additive no-max softmax partials (fp32 atomics),
// combine fused into RMSNorm.
// B=2 S=2048 E=1024 H=8 DH=128 F=64.
// ws layout (exactly 64 MB, proven size in R1):
//   [Oacc 32MB f32 (xb bf16 overlays first 8MB, dead before zero_ws)]
//   [wob 2MB][wqb 2MB <- Lacc 256KB overlays after gemm_qkv][wkb 2][wvb 2]
//   [Qb 8MB <- Nb overlays after attn][Kb 8MB][Vtb 8MB]

#define SDIM 2048
#define EDIM 1024
#define HDIM 8
#define DHDIM 128

typedef unsigned short u16;
typedef __attribute__((ext_vector_type(8))) short bf16x8;
typedef __attribute__((ext_vector_type(4))) u16 u16x4;
typedef __attribute__((ext_vector_type(8))) u16 u16x8;
typedef __attribute__((ext_vector_type(4))) float f32x4;

__device__ __forceinline__ u16 bf16rne(float f) {
    unsigned int u = __float_as_uint(f);
    u += 0x7fff + ((u >> 16) & 1);
    return (u16)(u >> 16);
}

__device__ __forceinline__ void gload16(void* lds, const void* g) {
    __builtin_amdgcn_global_load_lds(
        (const __attribute__((address_space(1))) unsigned int*)g,
        (__attribute__((address_space(3))) unsigned int*)lds, 16, 0, 0);
}

constexpr int GM = 4096, GN = 1024, GK = 1024;

// ------------------------------------------------------------------
// cast fp32 -> bf16: x (4M) + Wq/Wk/Wv/Wo (1M each).
// ------------------------------------------------------------------
__global__ __launch_bounds__(256) void cast_bf16(
    const float* __restrict__ x,  const float* __restrict__ wq,
    const float* __restrict__ wk, const float* __restrict__ wv,
    const float* __restrict__ wo,
    u16* __restrict__ xb,  u16* __restrict__ wqb, u16* __restrict__ wkb,
    u16* __restrict__ wvb, u16* __restrict__ wob)
{
    int bid = blockIdx.x;
    const float* src; u16* dst; int lb;
    if (bid < 2048)      { src = x;  dst = xb;  lb = bid; }
    else if (bid < 2560) { src = wq; dst = wqb; lb = bid - 2048; }
    else if (bid < 3072) { src = wk; dst = wkb; lb = bid - 2560; }
    else if (bid < 3584) { src = wv; dst = wvb; lb = bid - 3072; }
    else                 { src = wo; dst = wob; lb = bid - 3584; }
    size_t i = ((size_t)lb * 256 + threadIdx.x) * 8;
    float4 a = *(const float4*)&src[i];
    float4 b = *(const float4*)&src[i + 4];
    u16x8 o;
    o[0] = bf16rne(a.x); o[1] = bf16rne(a.y); o[2] = bf16rne(a.z); o[3] = bf16rne(a.w);
    o[4] = bf16rne(b.x); o[5] = bf16rne(b.y); o[6] = bf16rne(b.z); o[7] = bf16rne(b.w);
    *(u16x8*)&dst[i] = o;
}

// ------------------------------------------------------------------
// zero Oacc (8.39M f32) + Lacc (64K f32)
// ------------------------------------------------------------------
__global__ __launch_bounds__(256) void zero_ws(
    float* __restrict__ Oacc, float* __restrict__ Lacc)
{
    int bid = blockIdx.x;
    const f32x4 z = (f32x4){0.f, 0.f, 0.f, 0.f};
    if (bid < 8192) {
        *(f32x4*)&Oacc[((size_t)bid * 256 + threadIdx.x) * 4] = z;
    } else {
        *(f32x4*)&Lacc[((size_t)(bid - 8192) * 256 + threadIdx.x) * 4] = z;
    }
}

// ------------------------------------------------------------------
// bf16 MFMA GEMM core (unchanged from R3): C = A @ W^T, 128x128, BK=32.
// ------------------------------------------------------------------
struct GemmCore {
    f32x4 acc[4][4];
    int m0, n0, wm, wn, ln, quad;
};

__device__ __forceinline__ void gemm_core(
    GemmCore& g, const u16* __restrict__ A, const u16* __restrict__ W,
    u16* AsBase, u16* BsBase)
{
    const int tid = threadIdx.x;
    const int lane = tid & 63;
    const int wv = tid >> 6;
    g.ln = lane & 15; g.quad = lane >> 4;
    g.wm = (wv >> 1) * 64; g.wn = (wv & 1) * 64;
    g.m0 = blockIdx.y * 128; g.n0 = blockIdx.x * 128;

#pragma unroll
    for (int i = 0; i < 4; ++i)
#pragma unroll
        for (int j = 0; j < 4; ++j)
            g.acc[i][j] = (f32x4){0.f, 0.f, 0.f, 0.f};

    const int s0 = tid, s1 = tid + 256;
    const int ar0 = s0 >> 2, ac0 = (((s0 & 3) ^ ((ar0 >> 1) & 3)) * 8);
    const int ar1 = s1 >> 2, ac1 = (((s1 & 3) ^ ((ar1 >> 1) & 3)) * 8);
    const u16* pa0 = A + (size_t)(g.m0 + ar0) * GK + ac0;
    const u16* pa1 = A + (size_t)(g.m0 + ar1) * GK + ac1;
    const u16* pb0 = W + (size_t)(g.n0 + ar0) * GK + ac0;
    const u16* pb1 = W + (size_t)(g.n0 + ar1) * GK + ac1;
    u16* la0 = AsBase + s0 * 8; u16* la1 = AsBase + s1 * 8;
    u16* lb0 = BsBase + s0 * 8; u16* lb1 = BsBase + s1 * 8;

    const int roff = ((g.quad ^ ((g.ln >> 1) & 3)) * 8);

    for (int k0 = 0; k0 < GK; k0 += 32) {
        gload16(la0, pa0 + k0);
        gload16(la1, pa1 + k0);
        gload16(lb0, pb0 + k0);
        gload16(lb1, pb1 + k0);
        __syncthreads();

        bf16x8 af[4], bfr[4];
#pragma unroll
        for (int t = 0; t < 4; ++t) {
            af[t]  = *(const bf16x8*)&AsBase[(g.wm + t * 16 + g.ln) * 32 + roff];
            bfr[t] = *(const bf16x8*)&BsBase[(g.wn + t * 16 + g.ln) * 32 + roff];
        }
#pragma unroll
        for (int i = 0; i < 4; ++i)
#pragma unroll
            for (int j = 0; j < 4; ++j)
                g.acc[i][j] = __builtin_amdgcn_mfma_f32_16x16x32_bf16(
                    af[i], bfr[j], g.acc[i][j], 0, 0, 0);
        __syncthreads();
    }
}

// z=0 -> Qb (bf16 row), z=1 -> Kb, z=2 -> Vt transposed [bh][dh][s]
__global__ __launch_bounds__(256) void gemm_qkv(
    const u16* __restrict__ A,
    const u16* __restrict__ W0, const u16* __restrict__ W1, const u16* __restrict__ W2,
    u16* __restrict__ Qb, u16* __restrict__ Kb, u16* __restrict__ Vtb)
{
    __shared__ u16 As[128 * 32];
    __shared__ u16 Bs[128 * 32];
    const int z = blockIdx.z;
    const u16* W = (z == 0) ? W0 : ((z == 1) ? W1 : W2);
    GemmCore g;
    gemm_core(g, A, W, As, Bs);

    if (z < 2) {
        u16* C = (z == 0) ? Qb : Kb;
#pragma unroll
        for (int i = 0; i < 4; ++i) {
            int rb = g.m0 + g.wm + i * 16 + g.quad * 4;
#pragma unroll
            for (int r = 0; r < 4; ++r) {
                u16* crow = C + (size_t)(rb + r) * GN + g.n0 + g.wn + g.ln;
#pragma unroll
                for (int j = 0; j < 4; ++j)
                    crow[j * 16] = bf16rne(g.acc[i][j][r]);
            }
        }
    } else {
        const int bb = g.m0 >> 11;
        const int sb = (g.m0 & 2047) + g.wm + g.quad * 4;
#pragma unroll
        for (int j = 0; j < 4; ++j) {
            int dhg = g.n0 + g.wn + j * 16 + g.ln;
            int hh = dhg >> 7, dh = dhg & 127;
            u16* vrow = Vtb + ((size_t)(bb * 8 + hh) * DHDIM + dh) * SDIM + sb;
#pragma unroll
            for (int i = 0; i < 4; ++i) {
                u16x4 pk;
#pragma unroll
                for (int r = 0; r < 4; ++r) pk[r] = bf16rne(g.acc[i][j][r]);
                *(u16x4*)&vrow[i * 16] = pk;
            }
        }
    }
}

// out = (A @ W.T + bias) * (1-dw), fp32 output
__global__ __launch_bounds__(256) void gemm_out(
    const u16* __restrict__ A, const u16* __restrict__ W,
    float* __restrict__ C, const float* __restrict__ bias,
    const float* __restrict__ dwp)
{
    __shared__ u16 As[128 * 32];
    __shared__ u16 Bs[128 * 32];
    GemmCore g;
    gemm_core(g, A, W, As, Bs);

    const float scale = 1.0f - dwp[0];
    float bv[4];
#pragma unroll
    for (int j = 0; j < 4; ++j) bv[j] = bias[g.n0 + g.wn + j * 16 + g.ln];
#pragma unroll
    for (int i = 0; i < 4; ++i) {
        int rb = g.m0 + g.wm + i * 16 + g.quad * 4;
#pragma unroll
        for (int r = 0; r < 4; ++r) {
            float* crow = C + (size_t)(rb + r) * GN + g.n0 + g.wn + g.ln;
#pragma unroll
            for (int j = 0; j < 4; ++j)
                crow[j * 16] = (g.acc[i][j][r] + bv[j]) * scale;
        }
    }
}

// ------------------------------------------------------------------
// MFMA diff attention v2. Block = 4 waves (256 thr), 64 q rows.
// Grid (32 qtiles, 16 bh, 2 kv-parts). Each block: 1024 kv, 32 iters.
// K tile 32x128 and V tile 128x32 staged to LDS via global_load_lds
// with XOR chunk swizzle (conflict-free ds_read_b128 fragments).
// P transpose is wave-private LDS (no barrier). Partial (acc,l) are
// additive (no-max softmax) -> fp32 atomicAdd into Oacc/Lacc.
// ------------------------------------------------------------------
__global__ __launch_bounds__(256, 3) void attn_mfma(
    const u16* __restrict__ Qb, const u16* __restrict__ Kb,
    const u16* __restrict__ Vtb,
    float* __restrict__ Oacc, float* __restrict__ Lacc)
{
    __shared__ u16 Ks[512 * 8];            // 32 kv x 16 chunks (swizzled)
    __shared__ u16 Vs[512 * 8];            // 128 dh x 4 chunks (swizzled)
    __shared__ float Ps[4][2][16][36];     // per-wave P [br][qrow][kv]

    const int tid = threadIdx.x;
    const int wv   = tid >> 6;
    const int lane = tid & 63;
    const int ln = lane & 15, quad = lane >> 4;
    const int bh = blockIdx.y, b = bh >> 3, h = bh & 7;
    const int q0 = blockIdx.x * 64 + wv * 16;
    const int kvbase = blockIdx.z * 1024;

    // Q A-fragments (held all kernel): feats br*64 + kb*32 + quad*8
    const size_t qoff = (size_t)b * SDIM * EDIM + h * DHDIM;
    const u16* qp = Qb + qoff + (size_t)(q0 + ln) * EDIM + quad * 8;
    bf16x8 aq[2][2];
    aq[0][0] = *(const bf16x8*)(qp);
    aq[0][1] = *(const bf16x8*)(qp + 32);
    aq[1][0] = *(const bf16x8*)(qp + 64);
    aq[1][1] = *(const bf16x8*)(qp + 96);

    // staging maps: K slot s -> row s>>4, lds chunk s&15, global chunk ^(row&7)
    //               V slot s -> row s>>2, lds chunk s&3,  global chunk ^((row>>1)&3)
    const int sA = tid, sB = tid + 256;
    const int krA = sA >> 4, kcA = ((sA & 15) ^ (krA & 7)) * 8;
    const int krB = sB >> 4, kcB = ((sB & 15) ^ (krB & 7)) * 8;
    const u16* kgA = Kb + ((size_t)(b * SDIM + kvbase + krA)) * EDIM + h * DHDIM + kcA;
    const u16* kgB = Kb + ((size_t)(b * SDIM + kvbase + krB)) * EDIM + h * DHDIM + kcB;
    const int vrA = sA >> 2, vcA = ((sA & 3) ^ ((vrA >> 1) & 3)) * 8;
    const int vrB = sB >> 2, vcB = ((sB & 3) ^ ((vrB >> 1) & 3)) * 8;
    const u16* vgA = Vtb + ((size_t)bh * DHDIM + vrA) * SDIM + kvbase + vcA;
    const u16* vgB = Vtb + ((size_t)bh * DHDIM + vrB) * SDIM + kvbase + vcB;
    u16* ksA = Ks + sA * 8; u16* ksB = Ks + sB * 8;
    u16* vsA = Vs + sA * 8; u16* vsB = Vs + sB * 8;

    f32x4 acc0[8], acc1[8];
#pragma unroll
    for (int d = 0; d < 8; ++d) {
        acc0[d] = (f32x4){0.f, 0.f, 0.f, 0.f};
        acc1[d] = (f32x4){0.f, 0.f, 0.f, 0.f};
    }
    f32x4 lsum0 = (f32x4){0.f, 0.f, 0.f, 0.f};
    f32x4 lsum1 = (f32x4){0.f, 0.f, 0.f, 0.f};

    const float Cs = 0.125f * 1.44269504f;   // scale * log2(e)
    const f32x4 z4 = (f32x4){0.f, 0.f, 0.f, 0.f};
    const int lx = ln & 7;                   // K swizzle key
    const int vsw = (quad ^ ((ln >> 1) & 3)) * 8;  // V chunk offset (halfwords)

    for (int it = 0; it < 32; ++it) {
        __syncthreads();                     // WAR on Ks/Vs
        gload16(ksA, kgA); gload16(ksB, kgB);
        gload16(vsA, vgA); gload16(vsB, vgB);
        kgA += 32 * EDIM; kgB += 32 * EDIM; vgA += 32; vgB += 32;
        __syncthreads();                     // staged data visible

        // ---- K B-fragments from LDS ----
        bf16x8 kf[2][2][2];                  // [nt][br][kb]
#pragma unroll
        for (int nt = 0; nt < 2; ++nt) {
            const int rb = (nt * 16 + ln) * 16;
#pragma unroll
            for (int br = 0; br < 2; ++br)
#pragma unroll
                for (int kb = 0; kb < 2; ++kb) {
                    int kc = br * 8 + kb * 4 + quad;
                    kf[nt][br][kb] = *(const bf16x8*)&Ks[(rb + (kc ^ lx)) * 8];
                }
        }

        // ---- QK^T ----
        f32x4 s00 = __builtin_amdgcn_mfma_f32_16x16x32_bf16(aq[0][0], kf[0][0][0], z4, 0, 0, 0);
        s00 = __builtin_amdgcn_mfma_f32_16x16x32_bf16(aq[0][1], kf[0][0][1], s00, 0, 0, 0);
        f32x4 s01 = __builtin_amdgcn_mfma_f32_16x16x32_bf16(aq[0][0], kf[1][0][0], z4, 0, 0, 0);
        s01 = __builtin_amdgcn_mfma_f32_16x16x32_bf16(aq[0][1], kf[1][0][1], s01, 0, 0, 0);
        f32x4 s10 = __builtin_amdgcn_mfma_f32_16x16x32_bf16(aq[1][0], kf[0][1][0], z4, 0, 0, 0);
        s10 = __builtin_amdgcn_mfma_f32_16x16x32_bf16(aq[1][1], kf[0][1][1], s10, 0, 0, 0);
        f32x4 s11 = __builtin_amdgcn_mfma_f32_16x16x32_bf16(aq[1][0], kf[1][1][0], z4, 0, 0, 0);
        s11 = __builtin_amdgcn_mfma_f32_16x16x32_bf16(aq[1][1], kf[1][1][1], s11, 0, 0, 0);

        // ---- exp (no-max) + wave-private P store ----
#pragma unroll
        for (int r = 0; r < 4; ++r) {
            float p;
            p = exp2f(s00[r] * Cs); lsum0[r] += p; Ps[wv][0][quad * 4 + r][ln]      = p;
            p = exp2f(s01[r] * Cs); lsum0[r] += p; Ps[wv][0][quad * 4 + r][16 + ln] = p;
            p = exp2f(s10[r] * Cs); lsum1[r] += p; Ps[wv][1][quad * 4 + r][ln]      = p;
            p = exp2f(s11[r] * Cs); lsum1[r] += p; Ps[wv][1][quad * 4 + r][16 + ln] = p;
        }

        // ---- read P as A-fragment (wave-internal, lgkmcnt-ordered) ----
        bf16x8 ap0, ap1;
        {
            const float* pr0 = &Ps[wv][0][ln][quad * 8];
            f32x4 lo = *(const f32x4*)pr0;
            f32x4 hi = *(const f32x4*)(pr0 + 4);
#pragma unroll
            for (int j = 0; j < 4; ++j) { ap0[j] = (short)bf16rne(lo[j]); ap0[4 + j] = (short)bf16rne(hi[j]); }
            const float* pr1 = &Ps[wv][1][ln][quad * 8];
            f32x4 lo1 = *(const f32x4*)pr1;
            f32x4 hi1 = *(const f32x4*)(pr1 + 4);
#pragma unroll
            for (int j = 0; j < 4; ++j) { ap1[j] = (short)bf16rne(lo1[j]); ap1[4 + j] = (short)bf16rne(hi1[j]); }
        }

        // ---- V B-fragments from LDS + PV ----
#pragma unroll
        for (int dt = 0; dt < 8; ++dt) {
            bf16x8 bvf = *(const bf16x8*)&Vs[(dt * 16 + ln) * 32 + vsw];
            acc0[dt] = __builtin_amdgcn_mfma_f32_16x16x32_bf16(ap0, bvf, acc0[dt], 0, 0, 0);
            acc1[dt] = __builtin_amdgcn_mfma_f32_16x16x32_bf16(ap1, bvf, acc1[dt], 0, 0, 0);
        }
    }

    // ---- reduce l over the 16 kv-cols ----
#pragma unroll
    for (int r = 0; r < 4; ++r) {
        float v0 = lsum0[r], v1 = lsum1[r];
        v0 += __shfl_xor(v0, 1, 16); v1 += __shfl_xor(v1, 1, 16);
        v0 += __shfl_xor(v0, 2, 16); v1 += __shfl_xor(v1, 2, 16);
        v0 += __shfl_xor(v0, 4, 16); v1 += __shfl_xor(v1, 4, 16);
        v0 += __shfl_xor(v0, 8, 16); v1 += __shfl_xor(v1, 8, 16);
        lsum0[r] = v0; lsum1[r] = v1;
    }

    // ---- atomic accumulation of partials ----
#pragma unroll
    for (int r = 0; r < 4; ++r) {
        size_t row = (size_t)(b * SDIM + q0 + quad * 4 + r);
        float* o0 = Oacc + ((row * 8 + h) * 2 + 0) * 128 + ln;
        float* o1 = Oacc + ((row * 8 + h) * 2 + 1) * 128 + ln;
#pragma unroll
        for (int dt = 0; dt < 8; ++dt) {
            atomicAdd(o0 + dt * 16, acc0[dt][r]);
            atomicAdd(o1 + dt * 16, acc1[dt][r]);
        }
    }
    if (ln == 0) {
        float* l0 = Lacc + (size_t)((b * 8 + h) * 2 + 0) * SDIM + q0 + quad * 4;
        float* l1 = Lacc + (size_t)((b * 8 + h) * 2 + 1) * SDIM + q0 + quad * 4;
#pragma unroll
        for (int r = 0; r < 4; ++r) {
            atomicAdd(l0 + r, lsum0[r]);
            atomicAdd(l1 + r, lsum1[r]);
        }
    }
}

// ------------------------------------------------------------------
// combine branches + RMSNorm -> bf16 normed. Grid 4096 rows x 256 thr.
// thread t: h = t>>5, dh chunk = (t&31)*4.
// ------------------------------------------------------------------
__global__ __launch_bounds__(256) void rms_combine(
    const float* __restrict__ Oacc, const float* __restrict__ Lacc,
    const float* __restrict__ nw, u16* __restrict__ Nb,
    const float* __restrict__ dwp)
{
    const int row = blockIdx.x;            // b*2048 + q
    const int tid = threadIdx.x;
    const int h = tid >> 5, dh0 = (tid & 31) * 4;
    const int b = row >> 11, q = row & 2047;

    size_t ob = ((size_t)row * 8 + h) * 2 * 128;
    f32x4 a0 = *(const f32x4*)&Oacc[ob + dh0];
    f32x4 a1 = *(const f32x4*)&Oacc[ob + 128 + dh0];
    float l0 = Lacc[(size_t)((b * 8 + h) * 2 + 0) * SDIM + q];
    float l1 = Lacc[(size_t)((b * 8 + h) * 2 + 1) * SDIM + q];
    const float dw = dwp[0];
    float inv0 = 1.0f / l0;
    float inv1 = dw / l1;
    float o[4];
#pragma unroll
    for (int k = 0; k < 4; ++k) o[k] = a0[k] * inv0 - a1[k] * inv1;

    float ss = o[0] * o[0] + o[1] * o[1] + o[2] * o[2] + o[3] * o[3];
    ss += __shfl_xor(ss, 1,  64);
    ss += __shfl_xor(ss, 2,  64);
    ss += __shfl_xor(ss, 4,  64);
    ss += __shfl_xor(ss, 8,  64);
    ss += __shfl_xor(ss, 16, 64);
    ss += __shfl_xor(ss, 32, 64);
    __shared__ float red[4];
    if ((tid & 63) == 0) red[tid >> 6] = ss;
    __syncthreads();
    float tot = red[0] + red[1] + red[2] + red[3];
    float rms = rsqrtf(tot * (1.0f / 1024.0f) + 1.1920929e-07f);

    float4 w = *(const float4*)&nw[tid * 4];
    u16x4 pk;
    pk[0] = bf16rne(o[0] * rms * w.x);
    pk[1] = bf16rne(o[1] * rms * w.y);
    pk[2] = bf16rne(o[2] * rms * w.z);
    pk[3] = bf16rne(o[3] * rms * w.w);
    *(u16x4*)&Nb[(size_t)row * EDIM + tid * 4] = pk;
}

// ------------------------------------------------------------------
extern "C" void kernel_launch(void* const* d_in, const int* in_sizes, int n_in,
                              void* d_out, int out_size, void* d_ws, size_t ws_size,
                              hipStream_t stream)
{
    const float* x   = (const float*)d_in[0];
    const float* Wq  = (const float*)d_in[1];
    const float* Wk  = (const float*)d_in[2];
    const float* Wv  = (const float*)d_in[3];
    const float* nw  = (const float*)d_in[4];
    const float* Wo  = (const float*)d_in[5];
    const float* bo  = (const float*)d_in[6];
    const float* dwp = (const float*)d_in[7];
    float* out = (float*)d_out;

    // ---- 64 MB workspace layout with overlays (see header comment) ----
    float* Oacc = (float*)d_ws;                          // 32 MB
    u16*  xb   = (u16*)d_ws;                             // overlays Oacc head
    u16*  wob  = (u16*)((char*)d_ws + 33554432);         // 2 MB
    u16*  wqb  = wob + 1048576;
    u16*  wkb  = wqb + 1048576;
    u16*  wvb  = wkb + 1048576;
    float* Lacc = (float*)wqb;                           // overlays wqb (dead)
    u16*  Qb   = wvb + 1048576;                          // 8 MB
    u16*  Kb   = Qb + 4194304;
    u16*  Vtb  = Kb + 4194304;
    u16*  Nb   = Qb;                                     // overlays Qb (dead)

    // 0. casts
    cast_bf16<<<4096, 256, 0, stream>>>(x, Wq, Wk, Wv, Wo,
                                        xb, wqb, wkb, wvb, wob);
    // 1. QKV projections (bf16 MFMA)
    gemm_qkv<<<dim3(GN / 128, GM / 128, 3), 256, 0, stream>>>(
        xb, wqb, wkb, wvb, Qb, Kb, Vtb);
    // 2. zero accumulators (after gemm_qkv: xb/wqb regions now dead)
    zero_ws<<<8256, 256, 0, stream>>>(Oacc, Lacc);
    // 3. MFMA diff attention, 2 kv-parts
    attn_mfma<<<dim3(SDIM / 64, 2 * HDIM, 2), 256, 0, stream>>>(
        Qb, Kb, Vtb, Oacc, Lacc);
    // 4. combine + RMSNorm -> bf16
    rms_combine<<<4096, 256, 0, stream>>>(Oacc, Lacc, nw, Nb, dwp);
    // 5. output projection (bf16 MFMA)
    gemm_out<<<dim3(GN / 128, GM / 128, 1), 256, 0, stream>>>(
        Nb, wob, out, bo, dwp);
}